// Round 7
// baseline (286.197 us; speedup 1.0000x reference)
//
#include <hip/hip_runtime.h>
#include <hip/hip_bf16.h>

#define LN_EPS 1e-5f

// ---------------- CSR build ----------------

__global__ __launch_bounds__(256) void hist_kernel(
    const int* __restrict__ ei, int* __restrict__ deg, int E)
{
    int e = blockIdx.x * 256 + threadIdx.x;
    if (e < E) atomicAdd(&deg[ei[E + e]], 1);
}

__global__ __launch_bounds__(256) void scan1_kernel(
    const int* __restrict__ deg, int* __restrict__ rowstart,
    int* __restrict__ tilesum, int n)
{
    __shared__ int wsum[4];
    int t = threadIdx.x;
    int base = blockIdx.x * 2048 + t * 8;
    int v[8]; int tsum = 0;
    #pragma unroll
    for (int i = 0; i < 8; ++i) { v[i] = (base + i < n) ? deg[base + i] : 0; tsum += v[i]; }
    int lane = t & 63, w = t >> 6;
    int sc = tsum;
    #pragma unroll
    for (int off = 1; off < 64; off <<= 1) {
        int y = __shfl_up(sc, off);
        if (lane >= off) sc += y;
    }
    if (lane == 63) wsum[w] = sc;
    __syncthreads();
    int woff = 0;
    for (int j = 0; j < w; ++j) woff += wsum[j];
    int run = woff + sc - tsum;
    #pragma unroll
    for (int i = 0; i < 8; ++i) { if (base + i < n) rowstart[base + i] = run; run += v[i]; }
    if (t == 255) tilesum[blockIdx.x] = wsum[0] + wsum[1] + wsum[2] + wsum[3];
}

__global__ void scan2_kernel(int* tilesum, int T)
{
    if (blockIdx.x == 0 && threadIdx.x == 0) {
        int run = 0;
        for (int i = 0; i < T; ++i) { int v = tilesum[i]; tilesum[i] = run; run += v; }
    }
}

__global__ __launch_bounds__(256) void scan3_kernel(
    int* __restrict__ rowstart, const int* __restrict__ tilesum, int n, int E)
{
    int i = blockIdx.x * 256 + threadIdx.x;
    if (i < n) rowstart[i] += tilesum[i >> 11];
    if (i == 0) rowstart[n] = E;
}

__global__ __launch_bounds__(256) void fill_kernel(
    const int* __restrict__ ei, const int* __restrict__ rowstart,
    int* __restrict__ cursor, int* __restrict__ esrc, int E)
{
    int e = blockIdx.x * 256 + threadIdx.x;
    if (e < E) {
        int dst = ei[E + e];
        int pos = rowstart[dst] + atomicAdd(&cursor[dst], 1);
        esrc[pos] = ei[e];
    }
}

// ---------------- gather: CSR mean-aggregate (round-3 proven) ----------------
__global__ __launch_bounds__(256) void gather_kernel(
    const float* __restrict__ x,
    const int*   __restrict__ rowstart,
    const int*   __restrict__ esrc,
    float* __restrict__ mean,
    int N)
{
    int tid  = threadIdx.x;
    int lane = tid & 63;
    int g    = lane >> 4;
    int l4   = (lane & 15) * 4;
    int node = blockIdx.x * 4 + (tid >> 6);
    if (node >= N) return;
    int s0 = rowstart[node], s1 = rowstart[node + 1];

    float4 a0 = make_float4(0.f, 0.f, 0.f, 0.f);
    float4 a1 = make_float4(0.f, 0.f, 0.f, 0.f);
    int e = s0 + g;
    for (; e + 4 < s1; e += 8) {
        int sA = esrc[e];
        int sB = esrc[e + 4];
        float4 va = *(const float4*)&x[(size_t)sA * 64 + l4];
        float4 vb = *(const float4*)&x[(size_t)sB * 64 + l4];
        a0.x += va.x; a0.y += va.y; a0.z += va.z; a0.w += va.w;
        a1.x += vb.x; a1.y += vb.y; a1.z += vb.z; a1.w += vb.w;
    }
    if (e < s1) {
        float4 va = *(const float4*)&x[(size_t)esrc[e] * 64 + l4];
        a0.x += va.x; a0.y += va.y; a0.z += va.z; a0.w += va.w;
    }
    a0.x += a1.x; a0.y += a1.y; a0.z += a1.z; a0.w += a1.w;

    a0.x += __shfl_xor(a0.x, 32); a0.y += __shfl_xor(a0.y, 32);
    a0.z += __shfl_xor(a0.z, 32); a0.w += __shfl_xor(a0.w, 32);
    a0.x += __shfl_xor(a0.x, 16); a0.y += __shfl_xor(a0.y, 16);
    a0.z += __shfl_xor(a0.z, 16); a0.w += __shfl_xor(a0.w, 16);

    if (g == 0) {
        float inv = 1.0f / fmaxf((float)(s1 - s0), 1.0f);
        float4 r = make_float4(a0.x * inv, a0.y * inv, a0.z * inv, a0.w * inv);
        *(float4*)&mean[(size_t)node * 64 + l4] = r;
    }
}

// ---------------- MLP + LayerNorm + ELU (thread=node, wave=j-quarter) ----------------
// Block = 256 threads = 4 waves over the SAME 64 nodes; wave w computes output
// channels j in [16w, 16w+16). Within a wave, every lane walks identical
// weight addresses -> s_load (weights cost 0 VGPRs; v_fmac's one SGPR operand).
// acc[16] constant-indexed -> registers. Grid = 1563 blocks x 4 waves = 6252
// waves (~24/CU) so SMEM latency is hidden by co-resident waves' fmacs —
// round 6's 1563-wave version stalled at 16% occupancy on s_load latency.
// LN: per-wave partial s/s^2 -> LDS -> barrier -> combine. The barrier also
// makes `mean` (aliasing `out`) safe: all reads precede it, stores follow.
__global__ __launch_bounds__(256, 4) void mlp_kernel(
    const float* __restrict__ x,
    const float* mean,              // aliases out - no restrict
    const float* __restrict__ Wl,
    const float* __restrict__ Wr,
    const float* __restrict__ bias,
    const float* __restrict__ gamma,
    const float* __restrict__ beta,
    float* out,
    int N)
{
    __shared__ float sp[4][64];
    __shared__ float sq[4][64];

    int lane = threadIdx.x & 63;
    int part = threadIdx.x >> 6;    // j-quarter, wave-uniform
    int nbase = blockIdx.x * 64;
    int node  = nbase + lane;
    bool act  = node < N;
    size_t row = (size_t)(act ? node : 0) * 64;

    const float* Wlp = Wl + part * 16 * 64;   // rows [16p, 16p+16), uniform
    const float* Wrp = Wr + part * 16 * 64;

    float acc[16];
    #pragma unroll
    for (int j = 0; j < 16; ++j) acc[j] = bias[part * 16 + j];  // s_load

    for (int c = 0; c < 8; ++c) {             // rolled: streams inputs
        float4 ma = *(const float4*)&mean[row + c * 8];
        float4 mb = *(const float4*)&mean[row + c * 8 + 4];
        float4 xa = *(const float4*)&x[row + c * 8];
        float4 xb = *(const float4*)&x[row + c * 8 + 4];
        float vm[8] = {ma.x, ma.y, ma.z, ma.w, mb.x, mb.y, mb.z, mb.w};
        float vx[8] = {xa.x, xa.y, xa.z, xa.w, xb.x, xb.y, xb.z, xb.w};
        const float* wlc = Wlp + c * 8;       // uniform base -> s_load
        const float* wrc = Wrp + c * 8;
        #pragma unroll
        for (int j = 0; j < 16; ++j) {
            #pragma unroll
            for (int d = 0; d < 8; ++d) {
                acc[j] += wlc[j * 64 + d] * vm[d]
                        + wrc[j * 64 + d] * vx[d];
            }
        }
    }

    // partial LN stats over this wave's 16 channels
    float s0 = 0.f, s1 = 0.f, q0 = 0.f, q1 = 0.f;
    #pragma unroll
    for (int j = 0; j < 8; ++j) {
        s0 += acc[j];     q0 += acc[j] * acc[j];
        s1 += acc[j + 8]; q1 += acc[j + 8] * acc[j + 8];
    }
    sp[part][lane] = s0 + s1;
    sq[part][lane] = q0 + q1;
    __syncthreads();

    float st = (sp[0][lane] + sp[1][lane]) + (sp[2][lane] + sp[3][lane]);
    float qt = (sq[0][lane] + sq[1][lane]) + (sq[2][lane] + sq[3][lane]);
    float mu  = st * (1.0f / 64.0f);
    float var = qt * (1.0f / 64.0f) - mu * mu;
    float r   = rsqrtf(var + LN_EPS);

    if (act) {
        #pragma unroll
        for (int cc = 0; cc < 4; ++cc) {
            float4 g4 = *(const float4*)&gamma[part * 16 + cc * 4];  // uniform
            float4 b4 = *(const float4*)&beta[part * 16 + cc * 4];
            float4 o;
            o.x = (acc[cc*4+0] - mu) * r * g4.x + b4.x;
            o.y = (acc[cc*4+1] - mu) * r * g4.y + b4.y;
            o.z = (acc[cc*4+2] - mu) * r * g4.z + b4.z;
            o.w = (acc[cc*4+3] - mu) * r * g4.w + b4.w;
            o.x = o.x > 0.f ? o.x : __expf(o.x) - 1.0f;
            o.y = o.y > 0.f ? o.y : __expf(o.y) - 1.0f;
            o.z = o.z > 0.f ? o.z : __expf(o.z) - 1.0f;
            o.w = o.w > 0.f ? o.w : __expf(o.w) - 1.0f;
            *(float4*)&out[(size_t)node * 64 + part * 16 + cc * 4] = o;
        }
    }
}

extern "C" void kernel_launch(void* const* d_in, const int* in_sizes, int n_in,
                              void* d_out, int out_size, void* d_ws, size_t ws_size,
                              hipStream_t stream) {
    const float* x     = (const float*)d_in[0];
    const int*   ei    = (const int*)  d_in[1];
    const float* Wl    = (const float*)d_in[2];
    const float* Wr    = (const float*)d_in[3];
    const float* bias  = (const float*)d_in[4];
    const float* gamma = (const float*)d_in[5];
    const float* beta  = (const float*)d_in[6];

    int N = in_sizes[0] / 64;
    int E = in_sizes[1] / 2;

    int* deg      = (int*)d_ws;            // N
    int* cursor   = deg + N;               // N
    int* rowstart = cursor + N;            // N+1
    int* tilesum  = rowstart + (N + 1);    // <=64
    int* esrc     = tilesum + 64;          // E
    float* mean   = (float*)d_out;         // N*64; mlp reads its rows pre-barrier

    hipMemsetAsync(deg, 0, (size_t)2 * N * sizeof(int), stream);

    int eblocks = (E + 255) / 256;
    hist_kernel<<<eblocks, 256, 0, stream>>>(ei, deg, E);

    int T = (N + 2047) / 2048;
    scan1_kernel<<<T, 256, 0, stream>>>(deg, rowstart, tilesum, N);
    scan2_kernel<<<1, 64, 0, stream>>>(tilesum, T);
    scan3_kernel<<<(N + 255) / 256, 256, 0, stream>>>(rowstart, tilesum, N, E);

    fill_kernel<<<eblocks, 256, 0, stream>>>(ei, rowstart, cursor, esrc, E);

    gather_kernel<<<(N + 3) / 4, 256, 0, stream>>>(x, rowstart, esrc, mean, N);

    mlp_kernel<<<(N + 63) / 64, 256, 0, stream>>>(x, mean, Wl, Wr, bias, gamma, beta,
                                                  (float*)d_out, N);
}

// Round 8
// 203.211 us; speedup vs baseline: 1.4084x; 1.4084x over previous
//
#include <hip/hip_runtime.h>
#include <hip/hip_bf16.h>

#define LN_EPS 1e-5f

// ---------------- CSR build ----------------

__global__ __launch_bounds__(256) void hist_kernel(
    const int* __restrict__ ei, int* __restrict__ deg, int E)
{
    int e = blockIdx.x * 256 + threadIdx.x;
    if (e < E) atomicAdd(&deg[ei[E + e]], 1);
}

__global__ __launch_bounds__(256) void scan1_kernel(
    const int* __restrict__ deg, int* __restrict__ rowstart,
    int* __restrict__ tilesum, int n)
{
    __shared__ int wsum[4];
    int t = threadIdx.x;
    int base = blockIdx.x * 2048 + t * 8;
    int v[8]; int tsum = 0;
    #pragma unroll
    for (int i = 0; i < 8; ++i) { v[i] = (base + i < n) ? deg[base + i] : 0; tsum += v[i]; }
    int lane = t & 63, w = t >> 6;
    int sc = tsum;
    #pragma unroll
    for (int off = 1; off < 64; off <<= 1) {
        int y = __shfl_up(sc, off);
        if (lane >= off) sc += y;
    }
    if (lane == 63) wsum[w] = sc;
    __syncthreads();
    int woff = 0;
    for (int j = 0; j < w; ++j) woff += wsum[j];
    int run = woff + sc - tsum;
    #pragma unroll
    for (int i = 0; i < 8; ++i) { if (base + i < n) rowstart[base + i] = run; run += v[i]; }
    if (t == 255) tilesum[blockIdx.x] = wsum[0] + wsum[1] + wsum[2] + wsum[3];
}

__global__ void scan2_kernel(int* tilesum, int T)
{
    if (blockIdx.x == 0 && threadIdx.x == 0) {
        int run = 0;
        for (int i = 0; i < T; ++i) { int v = tilesum[i]; tilesum[i] = run; run += v; }
    }
}

__global__ __launch_bounds__(256) void scan3_kernel(
    int* __restrict__ rowstart, const int* __restrict__ tilesum, int n, int E)
{
    int i = blockIdx.x * 256 + threadIdx.x;
    if (i < n) rowstart[i] += tilesum[i >> 11];
    if (i == 0) rowstart[n] = E;
}

__global__ __launch_bounds__(256) void fill_kernel(
    const int* __restrict__ ei, const int* __restrict__ rowstart,
    int* __restrict__ cursor, int* __restrict__ esrc, int E)
{
    int e = blockIdx.x * 256 + threadIdx.x;
    if (e < E) {
        int dst = ei[E + e];
        int pos = rowstart[dst] + atomicAdd(&cursor[dst], 1);
        esrc[pos] = ei[e];
    }
}

// ---------------- gather: CSR mean-aggregate (round-3 proven) ----------------
__global__ __launch_bounds__(256) void gather_kernel(
    const float* __restrict__ x,
    const int*   __restrict__ rowstart,
    const int*   __restrict__ esrc,
    float* __restrict__ mean,
    int N)
{
    int tid  = threadIdx.x;
    int lane = tid & 63;
    int g    = lane >> 4;
    int l4   = (lane & 15) * 4;
    int node = blockIdx.x * 4 + (tid >> 6);
    if (node >= N) return;
    int s0 = rowstart[node], s1 = rowstart[node + 1];

    float4 a0 = make_float4(0.f, 0.f, 0.f, 0.f);
    float4 a1 = make_float4(0.f, 0.f, 0.f, 0.f);
    int e = s0 + g;
    for (; e + 4 < s1; e += 8) {
        int sA = esrc[e];
        int sB = esrc[e + 4];
        float4 va = *(const float4*)&x[(size_t)sA * 64 + l4];
        float4 vb = *(const float4*)&x[(size_t)sB * 64 + l4];
        a0.x += va.x; a0.y += va.y; a0.z += va.z; a0.w += va.w;
        a1.x += vb.x; a1.y += vb.y; a1.z += vb.z; a1.w += vb.w;
    }
    if (e < s1) {
        float4 va = *(const float4*)&x[(size_t)esrc[e] * 64 + l4];
        a0.x += va.x; a0.y += va.y; a0.z += va.z; a0.w += va.w;
    }
    a0.x += a1.x; a0.y += a1.y; a0.z += a1.z; a0.w += a1.w;

    a0.x += __shfl_xor(a0.x, 32); a0.y += __shfl_xor(a0.y, 32);
    a0.z += __shfl_xor(a0.z, 32); a0.w += __shfl_xor(a0.w, 32);
    a0.x += __shfl_xor(a0.x, 16); a0.y += __shfl_xor(a0.y, 16);
    a0.z += __shfl_xor(a0.z, 16); a0.w += __shfl_xor(a0.w, 16);

    if (g == 0) {
        float inv = 1.0f / fmaxf((float)(s1 - s0), 1.0f);
        float4 r = make_float4(a0.x * inv, a0.y * inv, a0.z * inv, a0.w * inv);
        *(float4*)&mean[(size_t)node * 64 + l4] = r;
    }
}

// ---------------- MLP + LayerNorm + ELU (thread=node, wave=j-quarter) ----------------
// Block = 256 threads = 4 waves over the SAME 64 nodes; wave w computes output
// channels j in [16w, 16w+16). `part` goes through readfirstlane so the
// compiler PROVES weight addresses are wave-uniform -> s_load (round 7 bug:
// part = tid>>6 looked per-lane varying -> weights went through VMEM, SGPR
// count collapsed 80->32 and dur doubled). v_fmac uses its one SGPR operand;
// weights cost 0 VGPRs. acc[16] constant-indexed -> registers. 6252 waves
// (~24/CU) hide s_load latency. LN: per-wave partials -> LDS -> barrier ->
// combine. Barrier also legalizes `mean` aliasing `out` (reads before, stores
// after; blocks own disjoint row ranges).
__global__ __launch_bounds__(256, 4) void mlp_kernel(
    const float* __restrict__ x,
    const float* mean,              // aliases out - no restrict
    const float* __restrict__ Wl,
    const float* __restrict__ Wr,
    const float* __restrict__ bias,
    const float* __restrict__ gamma,
    const float* __restrict__ beta,
    float* out,
    int N)
{
    __shared__ float sp[4][64];
    __shared__ float sq[4][64];

    int lane = threadIdx.x & 63;
    int part = __builtin_amdgcn_readfirstlane(threadIdx.x >> 6); // SGPR-pinned
    int nbase = blockIdx.x * 64;
    int node  = nbase + lane;
    bool act  = node < N;
    size_t row = (size_t)(act ? node : 0) * 64;

    const float* Wlp = Wl + part * 16 * 64;   // provably uniform -> s_load
    const float* Wrp = Wr + part * 16 * 64;

    float acc[16];
    #pragma unroll
    for (int j = 0; j < 16; ++j) acc[j] = bias[part * 16 + j];  // s_load

    for (int c = 0; c < 8; ++c) {             // rolled: streams inputs
        float4 ma = *(const float4*)&mean[row + c * 8];
        float4 mb = *(const float4*)&mean[row + c * 8 + 4];
        float4 xa = *(const float4*)&x[row + c * 8];
        float4 xb = *(const float4*)&x[row + c * 8 + 4];
        float vm[8] = {ma.x, ma.y, ma.z, ma.w, mb.x, mb.y, mb.z, mb.w};
        float vx[8] = {xa.x, xa.y, xa.z, xa.w, xb.x, xb.y, xb.z, xb.w};
        const float* wlc = Wlp + c * 8;       // uniform base -> s_load
        const float* wrc = Wrp + c * 8;
        #pragma unroll
        for (int j = 0; j < 16; ++j) {
            #pragma unroll
            for (int d = 0; d < 8; ++d) {
                acc[j] += wlc[j * 64 + d] * vm[d]
                        + wrc[j * 64 + d] * vx[d];
            }
        }
    }

    // partial LN stats over this wave's 16 channels
    float s0 = 0.f, s1 = 0.f, q0 = 0.f, q1 = 0.f;
    #pragma unroll
    for (int j = 0; j < 8; ++j) {
        s0 += acc[j];     q0 += acc[j] * acc[j];
        s1 += acc[j + 8]; q1 += acc[j + 8] * acc[j + 8];
    }
    sp[part][lane] = s0 + s1;
    sq[part][lane] = q0 + q1;
    __syncthreads();

    float st = (sp[0][lane] + sp[1][lane]) + (sp[2][lane] + sp[3][lane]);
    float qt = (sq[0][lane] + sq[1][lane]) + (sq[2][lane] + sq[3][lane]);
    float mu  = st * (1.0f / 64.0f);
    float var = qt * (1.0f / 64.0f) - mu * mu;
    float r   = rsqrtf(var + LN_EPS);

    if (act) {
        #pragma unroll
        for (int cc = 0; cc < 4; ++cc) {
            float4 g4 = *(const float4*)&gamma[part * 16 + cc * 4];  // uniform
            float4 b4 = *(const float4*)&beta[part * 16 + cc * 4];
            float4 o;
            o.x = (acc[cc*4+0] - mu) * r * g4.x + b4.x;
            o.y = (acc[cc*4+1] - mu) * r * g4.y + b4.y;
            o.z = (acc[cc*4+2] - mu) * r * g4.z + b4.z;
            o.w = (acc[cc*4+3] - mu) * r * g4.w + b4.w;
            o.x = o.x > 0.f ? o.x : __expf(o.x) - 1.0f;
            o.y = o.y > 0.f ? o.y : __expf(o.y) - 1.0f;
            o.z = o.z > 0.f ? o.z : __expf(o.z) - 1.0f;
            o.w = o.w > 0.f ? o.w : __expf(o.w) - 1.0f;
            *(float4*)&out[(size_t)node * 64 + part * 16 + cc * 4] = o;
        }
    }
}

extern "C" void kernel_launch(void* const* d_in, const int* in_sizes, int n_in,
                              void* d_out, int out_size, void* d_ws, size_t ws_size,
                              hipStream_t stream) {
    const float* x     = (const float*)d_in[0];
    const int*   ei    = (const int*)  d_in[1];
    const float* Wl    = (const float*)d_in[2];
    const float* Wr    = (const float*)d_in[3];
    const float* bias  = (const float*)d_in[4];
    const float* gamma = (const float*)d_in[5];
    const float* beta  = (const float*)d_in[6];

    int N = in_sizes[0] / 64;
    int E = in_sizes[1] / 2;

    int* deg      = (int*)d_ws;            // N
    int* cursor   = deg + N;               // N
    int* rowstart = cursor + N;            // N+1
    int* tilesum  = rowstart + (N + 1);    // <=64
    int* esrc     = tilesum + 64;          // E
    float* mean   = (float*)d_out;         // N*64; mlp reads its rows pre-barrier

    hipMemsetAsync(deg, 0, (size_t)2 * N * sizeof(int), stream);

    int eblocks = (E + 255) / 256;
    hist_kernel<<<eblocks, 256, 0, stream>>>(ei, deg, E);

    int T = (N + 2047) / 2048;
    scan1_kernel<<<T, 256, 0, stream>>>(deg, rowstart, tilesum, N);
    scan2_kernel<<<1, 64, 0, stream>>>(tilesum, T);
    scan3_kernel<<<(N + 255) / 256, 256, 0, stream>>>(rowstart, tilesum, N, E);

    fill_kernel<<<eblocks, 256, 0, stream>>>(ei, rowstart, cursor, esrc, E);

    gather_kernel<<<(N + 3) / 4, 256, 0, stream>>>(x, rowstart, esrc, mean, N);

    mlp_kernel<<<(N + 63) / 64, 256, 0, stream>>>(x, mean, Wl, Wr, bias, gamma, beta,
                                                  (float*)d_out, N);
}